// Round 9
// baseline (407.244 us; speedup 1.0000x reference)
//
#include <hip/hip_runtime.h>
#include <math.h>

#define BB 32
#define NN 4096
#define DD 512
#define ROWS_PER_WAVE 16   // 8192 waves * 16 rows = 131072 = B*N
#define WAVES_TOTAL (BB * NN / ROWS_PER_WAVE)       // 8192
#define WAVES_PER_BATCH (NN / ROWS_PER_WAVE)        // 256
#define BLOCKS_PER_BATCH 64
#define ENT_CAP 1024       // LDS compaction cap; global fallback beyond

typedef float v4f __attribute__((ext_vector_type(4)));

// 5-stage butterfly over a 32-lane half-wave; all 32 lanes end with the sum.
__device__ __forceinline__ float half_reduce_add(float v) {
    v += __shfl_xor(v, 16, 64);
    v += __shfl_xor(v, 8, 64);
    v += __shfl_xor(v, 4, 64);
    v += __shfl_xor(v, 2, 64);
    v += __shfl_xor(v, 1, 64);
    return v;
}

__device__ __forceinline__ float dot4(v4f a, v4f b) {
    return a.x * b.x + a.y * b.y + a.z * b.z + a.w * b.w;
}

// Fused: streaming cosine-threshold scan (contiguous row fronts per batch)
// + per-batch gather by the LAST finishing block of that batch.
// ctr[b] is memset to 0 each call (launch below), so the block seeing
// old+1 == BLOCKS_PER_BATCH is the true last arriver of THIS call.
__global__ __launch_bounds__(256) void sim_fused_kernel(
    const float* __restrict__ q, const float* __restrict__ key,
    const unsigned char* __restrict__ mask, const float* __restrict__ value,
    int* __restrict__ wcount, int2* __restrict__ list,
    unsigned int* __restrict__ ctr, float* __restrict__ out)
{
    const int lane = threadIdx.x & 63;
    const int half = lane >> 5;
    const int l32  = lane & 31;
    const int wave = threadIdx.x >> 6;
    const int wg   = blockIdx.x * (blockDim.x >> 6) + wave;   // 0..8191
    const int b    = wg >> 8;                                 // 256 waves/batch
    const int w    = wg & 255;                                // wave within batch

    // ---- scan: stream keys, threshold, record passing rows ----
    const v4f* qr = reinterpret_cast<const v4f*>(q + (size_t)b * DD);
    v4f qv0 = qr[l32 + 0];
    v4f qv1 = qr[l32 + 32];
    v4f qv2 = qr[l32 + 64];
    v4f qv3 = qr[l32 + 96];
    float qq = dot4(qv0, qv0) + dot4(qv1, qv1) + dot4(qv2, qv2) + dot4(qv3, qv3);
    qq = half_reduce_add(qq);
    const float qn = sqrtf(qq);

    const bool leader = (l32 == 0);      // lanes 0 and 32
    int base = 0;                        // uniform running slot offset

#pragma unroll 2
    for (int i = 0; i < ROWS_PER_WAVE / 2; ++i) {
        const int n = 512 * i + 2 * w + half;        // row within batch
        const size_t row = (size_t)b * NN + n;
        const v4f* kr = reinterpret_cast<const v4f*>(key + row * DD);
        v4f k0 = __builtin_nontemporal_load(&kr[l32 + 0]);
        v4f k1 = __builtin_nontemporal_load(&kr[l32 + 32]);
        v4f k2 = __builtin_nontemporal_load(&kr[l32 + 64]);
        v4f k3 = __builtin_nontemporal_load(&kr[l32 + 96]);

        float dot = dot4(k0, qv0) + dot4(k1, qv1) + dot4(k2, qv2) + dot4(k3, qv3);
        float kk  = dot4(k0, k0) + dot4(k1, k1) + dot4(k2, k2) + dot4(k3, k3);

        dot = half_reduce_add(dot);
        kk  = half_reduce_add(kk);

        bool pass = false;
        float attn = 0.0f;
        if (leader) {
            float denom = fmaxf(qn * sqrtf(kk), 1e-8f);
            attn = dot / denom;
            pass = (attn >= 0.9f) && (mask[row] == 0);
        }
        unsigned long long bal = __ballot(pass);
        int lo = (int)(bal & 1ull);            // lane 0  passed?
        int hi = (int)((bal >> 32) & 1ull);    // lane 32 passed?
        if (pass) {
            int slot = base + ((lane == 32) ? lo : 0);
            list[(size_t)wg * ROWS_PER_WAVE + slot] =
                make_int2(n, __float_as_int(attn));
        }
        base += lo + hi;
    }

    if (lane == 0) wcount[wg] = base;

    // ---- completion protocol: last block of this batch does the gather ----
    __shared__ int s_last;
    __threadfence();           // release: list/wcount visible before the atomic
    __syncthreads();
    if (threadIdx.x == 0) {
        unsigned int old = atomicAdd(&ctr[b], 1u);
        s_last = (old + 1u == BLOCKS_PER_BATCH) ? 1 : 0;
    }
    __syncthreads();
    if (!s_last) return;
    __threadfence();           // acquire: see other blocks' list/wcount writes

    // ---- gather (256 threads, 2 output elems each) ----
    __shared__ int  s_wsum[4];
    __shared__ int  s_cnt[WAVES_PER_BATCH];
    __shared__ int2 s_ent[ENT_CAP];

    const int t = threadIdx.x;
    const int wbase = b * WAVES_PER_BATCH;
    int c = wcount[wbase + t];
    s_cnt[t] = c;

    int x = c;
    for (int d = 1; d < 64; d <<= 1) {
        int y = __shfl_up(x, d, 64);
        if ((t & 63) >= d) x += y;
    }
    if ((t & 63) == 63) s_wsum[t >> 6] = x;
    __syncthreads();

    int waveoff = 0;
    for (int wv = 0; wv < (t >> 6); ++wv) waveoff += s_wsum[wv];
    const int excl  = waveoff + x - c;                       // exclusive prefix
    const int total = s_wsum[0] + s_wsum[1] + s_wsum[2] + s_wsum[3];

    if (total <= ENT_CAP) {
        const int2* lw = &list[(size_t)(wbase + t) * ROWS_PER_WAVE];
        for (int j = 0; j < c; ++j) s_ent[excl + j] = lw[j];
    }
    __syncthreads();

    float asum = 0.0f, acc0 = 0.0f, acc1 = 0.0f;
    const float* vb = value + (size_t)b * NN * DD;
    if (total <= ENT_CAP) {
        for (int j = 0; j < total; ++j) {
            int2 e = s_ent[j];                 // LDS broadcast
            float a = __int_as_float(e.y);
            asum += a;
            const float* vr = vb + (size_t)e.x * DD;
            acc0 += a * vr[t];
            acc1 += a * vr[t + 256];
        }
    } else {                                   // pathological fallback, correct
        for (int w2 = 0; w2 < WAVES_PER_BATCH; ++w2) {
            int cw = s_cnt[w2];
            const int2* lw = &list[(size_t)(wbase + w2) * ROWS_PER_WAVE];
            for (int j = 0; j < cw; ++j) {
                int2 e = lw[j];
                float a = __int_as_float(e.y);
                asum += a;
                const float* vr = vb + (size_t)e.x * DD;
                acc0 += a * vr[t];
                acc1 += a * vr[t + 256];
            }
        }
    }
    const float inv = 1.0f / (asum + 1e-8f);
    out[(size_t)b * DD + t]       = acc0 * inv;
    out[(size_t)b * DD + t + 256] = acc1 * inv;
}

extern "C" void kernel_launch(void* const* d_in, const int* in_sizes, int n_in,
                              void* d_out, int out_size, void* d_ws, size_t ws_size,
                              hipStream_t stream) {
    const float* query = (const float*)d_in[0];                // [B, D]
    const float* key   = (const float*)d_in[1];                // [B, N, D]
    const float* value = (const float*)d_in[2];                // [B, N, D]
    const unsigned char* mask = (const unsigned char*)d_in[3]; // [B, N] bool
    float* out = (float*)d_out;                                // [B, D]

    char* ws = (char*)d_ws;
    unsigned int* ctr = (unsigned int*)(ws);                   // 32 u32
    int*  wcount = (int*)(ws + 256);                           // 8192 ints = 32 KiB
    int2* list   = (int2*)(ws + 256 + WAVES_TOTAL * 4);        // 8192*16 int2 = 1 MiB

    // Last-arriver election requires ctr == 0 at call start (residue is
    // call-invariant otherwise: each call adds exactly 64 per batch).
    (void)hipMemsetAsync(ctr, 0, BB * sizeof(unsigned int), stream);
    sim_fused_kernel<<<WAVES_TOTAL / 4, 256, 0, stream>>>(query, key, mask, value,
                                                          wcount, list, ctr, out);
}

// Round 10
// 52.292 us; speedup vs baseline: 7.7879x; 7.7879x over previous
//
#include <hip/hip_runtime.h>
#include <math.h>

#define BB 32
#define NN 4096
#define DD 512
#define ROWS_PER_WAVE 16                 // 8192 waves * 16 rows = 131072 = B*N
#define WAVES_TOTAL (BB * NN / ROWS_PER_WAVE)   // 8192
#define BLOCKS_PER_BATCH 64              // 256 waves/batch / 4 waves/block

typedef float v4f __attribute__((ext_vector_type(4)));

// 5-stage butterfly over a 32-lane half-wave; all 32 lanes end with the sum.
__device__ __forceinline__ float half_reduce_add(float v) {
    v += __shfl_xor(v, 16, 64);
    v += __shfl_xor(v, 8, 64);
    v += __shfl_xor(v, 4, 64);
    v += __shfl_xor(v, 2, 64);
    v += __shfl_xor(v, 1, 64);
    return v;
}

__device__ __forceinline__ float dot4(v4f a, v4f b) {
    return a.x * b.x + a.y * b.y + a.z * b.z + a.w * b.w;
}

// Scan + LOCAL gather. Batch b is owned by 64 blocks (256 waves); at
// iteration i those waves read the contiguous row front [512i, 512i+512).
// Passing rows are collected in block-local LDS (LDS atomic slot assign);
// after the scan each block gathers ITS OWN rows' value vectors and writes
// an unconditional partial [512] + partial asum. No global atomics, no
// fences, no zeroing: every partial is written every call.
__global__ __launch_bounds__(256) void sim_scan_kernel(
    const float* __restrict__ q, const float* __restrict__ key,
    const unsigned char* __restrict__ mask, const float* __restrict__ value,
    float* __restrict__ partial, float* __restrict__ asum_p)
{
    __shared__ int  s_cnt;
    __shared__ int2 s_ent[BLOCKS_PER_BATCH];   // block owns 64 rows max

    const int lane = threadIdx.x & 63;
    const int half = lane >> 5;
    const int l32  = lane & 31;
    const int wave = threadIdx.x >> 6;
    const int wg   = blockIdx.x * 4 + wave;      // 0..8191
    const int b    = wg >> 8;                    // 256 waves/batch
    const int w    = wg & 255;                   // wave within batch

    if (threadIdx.x == 0) s_cnt = 0;
    __syncthreads();

    const v4f* qr = reinterpret_cast<const v4f*>(q + (size_t)b * DD);
    v4f qv0 = qr[l32 + 0];
    v4f qv1 = qr[l32 + 32];
    v4f qv2 = qr[l32 + 64];
    v4f qv3 = qr[l32 + 96];
    float qq = dot4(qv0, qv0) + dot4(qv1, qv1) + dot4(qv2, qv2) + dot4(qv3, qv3);
    qq = half_reduce_add(qq);
    const float qn = sqrtf(qq);

    const bool leader = (l32 == 0);              // lanes 0 and 32

#pragma unroll 2
    for (int i = 0; i < ROWS_PER_WAVE / 2; ++i) {
        const int n = 512 * i + 2 * w + half;    // row within batch
        const size_t row = (size_t)b * NN + n;
        const v4f* kr = reinterpret_cast<const v4f*>(key + row * DD);
        v4f k0 = __builtin_nontemporal_load(&kr[l32 + 0]);
        v4f k1 = __builtin_nontemporal_load(&kr[l32 + 32]);
        v4f k2 = __builtin_nontemporal_load(&kr[l32 + 64]);
        v4f k3 = __builtin_nontemporal_load(&kr[l32 + 96]);

        float dot = dot4(k0, qv0) + dot4(k1, qv1) + dot4(k2, qv2) + dot4(k3, qv3);
        float kk  = dot4(k0, k0) + dot4(k1, k1) + dot4(k2, k2) + dot4(k3, k3);

        dot = half_reduce_add(dot);
        kk  = half_reduce_add(kk);

        if (leader) {
            float denom = fmaxf(qn * sqrtf(kk), 1e-8f);
            float attn  = dot / denom;
            if (attn >= 0.9f && mask[row] == 0) {
                int slot = atomicAdd(&s_cnt, 1);      // LDS atomic (block-local)
                s_ent[slot] = make_int2(n, __float_as_int(attn));
            }
        }
    }

    __syncthreads();

    // ---- local gather: this block's rows only (usually 0, ~8 for block 0) ----
    const int t = threadIdx.x;
    const int c = s_cnt;
    float asum = 0.0f, acc0 = 0.0f, acc1 = 0.0f;
    const float* vb = value + (size_t)b * NN * DD;
    for (int j = 0; j < c; ++j) {
        int2 e = s_ent[j];                       // LDS broadcast
        float a = __int_as_float(e.y);
        asum += a;
        const float* vr = vb + (size_t)e.x * DD;
        acc0 += a * vr[t];
        acc1 += a * vr[t + 256];
    }
    float* pr = partial + (size_t)blockIdx.x * DD;   // blockIdx.x == b*64+blk
    pr[t]       = acc0;
    pr[t + 256] = acc1;
    if (t == 0) asum_p[blockIdx.x] = asum;
}

// Combine: out[b][d] = sum_j partial[b*64+j][d] / (sum_j asum_p[b*64+j] + 1e-8).
// Reads 4 MB of just-written partials (L2/L3-hot). 32 blocks x 512 threads.
__global__ __launch_bounds__(512) void sim_combine_kernel(
    const float* __restrict__ partial, const float* __restrict__ asum_p,
    float* __restrict__ out)
{
    const int b = blockIdx.x;
    const int d = threadIdx.x;
    float s = 0.0f;
#pragma unroll 8
    for (int j = 0; j < BLOCKS_PER_BATCH; ++j)
        s += partial[(size_t)(b * BLOCKS_PER_BATCH + j) * DD + d];
    float a = 0.0f;
#pragma unroll 8
    for (int j = 0; j < BLOCKS_PER_BATCH; ++j)
        a += asum_p[b * BLOCKS_PER_BATCH + j];
    out[(size_t)b * DD + d] = s / (a + 1e-8f);
}

extern "C" void kernel_launch(void* const* d_in, const int* in_sizes, int n_in,
                              void* d_out, int out_size, void* d_ws, size_t ws_size,
                              hipStream_t stream) {
    const float* query = (const float*)d_in[0];                // [B, D]
    const float* key   = (const float*)d_in[1];                // [B, N, D]
    const float* value = (const float*)d_in[2];                // [B, N, D]
    const unsigned char* mask = (const unsigned char*)d_in[3]; // [B, N] bool
    float* out = (float*)d_out;                                // [B, D]

    char* ws = (char*)d_ws;
    float* partial = (float*)(ws);                             // 2048*512 f32 = 4 MiB
    float* asum_p  = (float*)(ws + (size_t)WAVES_TOTAL / 4 * DD * 4);  // 2048 f32

    sim_scan_kernel<<<WAVES_TOTAL / 4, 256, 0, stream>>>(query, key, mask, value,
                                                         partial, asum_p);
    sim_combine_kernel<<<BB, DD, 0, stream>>>(partial, asum_p, out);
}

// Round 11
// 46.883 us; speedup vs baseline: 8.6864x; 1.1154x over previous
//
#include <hip/hip_runtime.h>
#include <math.h>

#define BB 32
#define NN 4096
#define DD 512
#define ROWS_PER_WAVE 16   // 8192 waves * 16 rows = 131072 = B*N
#define WAVES_TOTAL (BB * NN / ROWS_PER_WAVE)       // 8192
#define WAVES_PER_BATCH (NN / ROWS_PER_WAVE)        // 256

typedef float v4f __attribute__((ext_vector_type(4)));

// 5-stage butterfly over a 32-lane half-wave; all 32 lanes end with the sum.
__device__ __forceinline__ float half_reduce_add(float v) {
    v += __shfl_xor(v, 16, 64);
    v += __shfl_xor(v, 8, 64);
    v += __shfl_xor(v, 4, 64);
    v += __shfl_xor(v, 2, 64);
    v += __shfl_xor(v, 1, 64);
    return v;
}

__device__ __forceinline__ float dot4(v4f a, v4f b) {
    return a.x * b.x + a.y * b.y + a.z * b.z + a.w * b.w;
}

// Batch b is owned by 256 waves. At iteration i those waves read the
// CONTIGUOUS row front [512*i, 512*i+512) of that batch (2 rows per wave,
// half-wave per row, 64 B/lane) -> ~32 large sequential DRAM streams
// instead of 8192 scattered ones. Passing rows go to the wave's PRIVATE
// slot range; count written unconditionally -> no atomics, no memset.
__global__ __launch_bounds__(256) void sim_pass1_kernel(
    const float* __restrict__ q, const float* __restrict__ key,
    const unsigned char* __restrict__ mask,
    int* __restrict__ wcount, int2* __restrict__ list)
{
    const int lane = threadIdx.x & 63;
    const int half = lane >> 5;
    const int l32  = lane & 31;
    const int wave = threadIdx.x >> 6;
    const int wg   = blockIdx.x * (blockDim.x >> 6) + wave;   // 0..8191
    const int b    = wg >> 8;                                 // 256 waves/batch
    const int w    = wg & 255;                                // wave within batch

    // Load q once per wave (both halves load identical data).
    const v4f* qr = reinterpret_cast<const v4f*>(q + (size_t)b * DD);
    v4f qv0 = qr[l32 + 0];
    v4f qv1 = qr[l32 + 32];
    v4f qv2 = qr[l32 + 64];
    v4f qv3 = qr[l32 + 96];
    float qq = dot4(qv0, qv0) + dot4(qv1, qv1) + dot4(qv2, qv2) + dot4(qv3, qv3);
    qq = half_reduce_add(qq);
    const float qn = sqrtf(qq);

    const bool leader = (l32 == 0);      // lanes 0 and 32
    int base = 0;                        // uniform running slot offset

#pragma unroll 2
    for (int i = 0; i < ROWS_PER_WAVE / 2; ++i) {
        const int n = 512 * i + 2 * w + half;        // row within batch
        const size_t row = (size_t)b * NN + n;
        const v4f* kr = reinterpret_cast<const v4f*>(key + row * DD);
        v4f k0 = __builtin_nontemporal_load(&kr[l32 + 0]);
        v4f k1 = __builtin_nontemporal_load(&kr[l32 + 32]);
        v4f k2 = __builtin_nontemporal_load(&kr[l32 + 64]);
        v4f k3 = __builtin_nontemporal_load(&kr[l32 + 96]);

        float dot = dot4(k0, qv0) + dot4(k1, qv1) + dot4(k2, qv2) + dot4(k3, qv3);
        float kk  = dot4(k0, k0) + dot4(k1, k1) + dot4(k2, k2) + dot4(k3, k3);

        dot = half_reduce_add(dot);
        kk  = half_reduce_add(kk);

        bool pass = false;
        float attn = 0.0f;
        if (leader) {
            float denom = fmaxf(qn * sqrtf(kk), 1e-8f);
            attn = dot / denom;
            pass = (attn >= 0.9f) && (mask[row] == 0);
        }
        unsigned long long bal = __ballot(pass);
        int lo = (int)(bal & 1ull);            // lane 0  (row n, half 0) passed?
        int hi = (int)((bal >> 32) & 1ull);    // lane 32 (row n+1, half 1) passed?
        if (pass) {
            int slot = base + ((lane == 32) ? lo : 0);
            list[(size_t)wg * ROWS_PER_WAVE + slot] =
                make_int2(n, __float_as_int(attn));
        }
        base += lo + hi;
    }

    if (lane == 0) wcount[wg] = base;
}

// One block per batch. Parallel compaction: threads 0..255 load the 256
// per-wave counts (one coalesced load), LDS+shfl prefix-sum, copy private
// entries into a compacted LDS array; then all 512 threads gather value rows.
__global__ __launch_bounds__(512) void sim_pass2_kernel(
    const float* __restrict__ value, const int* __restrict__ wcount,
    const int2* __restrict__ list, float* __restrict__ out)
{
    __shared__ int  s_wsum[4];
    __shared__ int  s_total;
    __shared__ int2 s_ent[NN];     // worst-case all rows pass (32 KiB)

    const int b = blockIdx.x;
    const int t = threadIdx.x;
    const int wbase = b * WAVES_PER_BATCH;

    int c = (t < WAVES_PER_BATCH) ? wcount[wbase + t] : 0;

    // intra-wave inclusive prefix sum
    int x = c;
    for (int d = 1; d < 64; d <<= 1) {
        int y = __shfl_up(x, d, 64);
        if ((t & 63) >= d) x += y;
    }
    if (t < WAVES_PER_BATCH && (t & 63) == 63) s_wsum[t >> 6] = x;
    __syncthreads();

    if (t < WAVES_PER_BATCH) {
        int waveoff = 0;
        for (int w = 0; w < (t >> 6); ++w) waveoff += s_wsum[w];
        int excl = waveoff + x - c;            // exclusive prefix
        const int2* lw = &list[(size_t)(wbase + t) * ROWS_PER_WAVE];
        for (int j = 0; j < c; ++j) s_ent[excl + j] = lw[j];
        if (t == WAVES_PER_BATCH - 1) s_total = excl + c;
    }
    __syncthreads();

    const int total = s_total;
    float asum = 0.0f;
    float acc  = 0.0f;
    for (int j = 0; j < total; ++j) {
        int2 e = s_ent[j];                     // LDS broadcast
        float a = __int_as_float(e.y);
        asum += a;
        acc  += a * value[((size_t)b * NN + e.x) * DD + t];
    }
    out[(size_t)b * DD + t] = acc / (asum + 1e-8f);
}

extern "C" void kernel_launch(void* const* d_in, const int* in_sizes, int n_in,
                              void* d_out, int out_size, void* d_ws, size_t ws_size,
                              hipStream_t stream) {
    const float* query = (const float*)d_in[0];                // [B, D]
    const float* key   = (const float*)d_in[1];                // [B, N, D]
    const float* value = (const float*)d_in[2];                // [B, N, D]
    const unsigned char* mask = (const unsigned char*)d_in[3]; // [B, N] bool
    float* out = (float*)d_out;                                // [B, D]

    char* ws = (char*)d_ws;
    int*  wcount = (int*)(ws);                         // 8192 ints = 32 KiB
    int2* list   = (int2*)(ws + WAVES_TOTAL * 4);      // 8192*16 int2 = 1 MiB

    sim_pass1_kernel<<<WAVES_TOTAL / 4, 256, 0, stream>>>(query, key, mask,
                                                          wcount, list);
    sim_pass2_kernel<<<BB, DD, 0, stream>>>(value, wcount, list, out);
}